// Round 1
// baseline (352.637 us; speedup 1.0000x reference)
//
#include <hip/hip_runtime.h>
#include <math.h>

#define F      32
#define BATCH  2048
#define K      64
#define H      64
#define NPAIR  496     // 32*31/2
#define CHUNK  16      // pairs staged per chunk
#define NCHUNK 31      // 496/16

__global__ __launch_bounds__(256)
void afm_fwd(const int*   __restrict__ x,      // [F,B]
             const float* __restrict__ emb_v,  // [VOCAB,K]
             const float* __restrict__ at_w,   // [K,H]
             const float* __restrict__ at_b,   // [H]
             const float* __restrict__ at_h,   // [H,1]
             const float* __restrict__ p,      // [K,1]
             const float* __restrict__ w0,     // [1]
             const float* __restrict__ w1,     // [VOCAB,1]
             float*       __restrict__ out)    // [B]
{
    __shared__ float Vsh[F][K];        // 8 KB   embeddings for this b
    __shared__ float VVsh[CHUNK][K];   // 4 KB   staged pair products
    __shared__ unsigned char pi_sh[NPAIR], pj_sh[NPAIR];
    __shared__ float fm_sh[F];
    __shared__ float wacc[4];

    const int b    = blockIdx.x;
    const int t    = threadIdx.x;
    const int lane = t & 63;
    const int wv   = t >> 6;

    // ---- pair index tables (i<j, triu order) ----
    if (t < F) {
        int i = t;
        int base = i * (2 * F - i - 1) / 2;   // sum_{a<i} (F-1-a)
        for (int j = i + 1; j < F; ++j) {
            pi_sh[base + (j - i - 1)] = (unsigned char)i;
            pj_sh[base + (j - i - 1)] = (unsigned char)j;
        }
    }

    // ---- gather V rows for this b (coalesced 256B per row) ----
    #pragma unroll
    for (int r = 0; r < 8; ++r) {
        int f = (t >> 6) + 4 * r;              // wave-uniform
        int idx = x[f * BATCH + b];            // uniform -> s_load
        Vsh[f][lane] = emb_v[idx * K + lane];
    }
    // ---- first-order FM partials ----
    if (t < F) fm_sh[t] = w1[x[t * BATCH + b]];

    // ---- per-lane parameter preloads (lane doubles as h-index and k-index) ----
    float wcol[K];                             // at_w[:, lane] in registers
    #pragma unroll
    for (int k = 0; k < K; ++k) wcol[k] = at_w[k * H + lane];
    const float ah_reg = at_h[lane];
    const float ab_reg = at_b[lane];
    const float p_reg  = p[lane];

    __syncthreads();

    float acc = 0.f;
    for (int c = 0; c < NCHUNK; ++c) {
        // phase 1: all 4 waves cooperatively build VV for 16 pairs
        #pragma unroll
        for (int r = 0; r < 4; ++r) {
            int pp = (t >> 6) + 4 * r;         // 0..15
            int pr = c * CHUNK + pp;
            int i = pi_sh[pr], j = pj_sh[pr];
            VVsh[pp][lane] = Vsh[i][lane] * Vsh[j][lane];
        }
        __syncthreads();

        // phase 2: wave wv consumes pairs [wv*4, wv*4+4)
        #pragma unroll
        for (int u = 0; u < 4; ++u) {
            int pp = wv * 4 + u;
            float hid = ab_reg;                 // lane = h
            #pragma unroll
            for (int k4 = 0; k4 < K / 4; ++k4) {
                float4 vv = *(const float4*)(&VVsh[pp][k4 * 4]);  // broadcast b128
                hid = fmaf(vv.x, wcol[k4 * 4 + 0], hid);
                hid = fmaf(vv.y, wcol[k4 * 4 + 1], hid);
                hid = fmaf(vv.z, wcol[k4 * 4 + 2], hid);
                hid = fmaf(vv.w, wcol[k4 * 4 + 3], hid);
            }
            float sc = fmaxf(hid, 0.f) * ah_reg;   // score partial over h=lane
            float qp = VVsh[pp][lane] * p_reg;     // q partial over k=lane
            #pragma unroll
            for (int off = 32; off > 0; off >>= 1) {
                sc += __shfl_xor(sc, off, 64);
                qp += __shfl_xor(qp, off, 64);
            }
            acc += sc * qp;                        // same value in all lanes
        }
        __syncthreads();   // protect VVsh before next chunk overwrites
    }

    if (lane == 0) wacc[wv] = acc;
    __syncthreads();

    if (t == 0) {
        float fm1 = w0[0];
        #pragma unroll
        for (int f = 0; f < F; ++f) fm1 += fm_sh[f];
        float logit = wacc[0] + wacc[1] + wacc[2] + wacc[3] + fm1;
        out[b] = 1.f / (1.f + expf(-logit));
    }
}

extern "C" void kernel_launch(void* const* d_in, const int* in_sizes, int n_in,
                              void* d_out, int out_size, void* d_ws, size_t ws_size,
                              hipStream_t stream) {
    const int*   x     = (const int*)  d_in[0];
    const float* emb_v = (const float*)d_in[1];
    const float* at_w  = (const float*)d_in[2];
    const float* at_b  = (const float*)d_in[3];
    const float* at_h  = (const float*)d_in[4];
    const float* p     = (const float*)d_in[5];
    const float* w0    = (const float*)d_in[6];
    const float* w1    = (const float*)d_in[7];
    float* out = (float*)d_out;

    afm_fwd<<<BATCH, 256, 0, stream>>>(x, emb_v, at_w, at_b, at_h, p, w0, w1, out);
}

// Round 2
// 109.583 us; speedup vs baseline: 3.2180x; 3.2180x over previous
//
#include <hip/hip_runtime.h>
#include <math.h>

#define F      32
#define BATCH  2048
#define K      64
#define H      64
#define NPAIR  496     // 32*31/2
#define NTROW  31      // 496/16 pair-tile rows of 16

typedef float v4f __attribute__((ext_vector_type(4)));
typedef short v8s __attribute__((ext_vector_type(8)));

__device__ __forceinline__ float bf2f(short s) {
    union { unsigned u; float f; } v;
    v.u = ((unsigned)(unsigned short)s) << 16;
    return v.f;
}
__device__ __forceinline__ short f2bf(float f) {
    union { float f; unsigned u; } v; v.f = f;
    unsigned r = v.u + 0x7fffu + ((v.u >> 16) & 1u);   // RNE
    return (short)(r >> 16);
}

__global__ __launch_bounds__(256)
void afm_fwd(const int*   __restrict__ x,      // [F,B]
             const float* __restrict__ emb_v,  // [VOCAB,K]
             const float* __restrict__ at_w,   // [K,H]
             const float* __restrict__ at_b,   // [H]
             const float* __restrict__ at_h,   // [H,1]
             const float* __restrict__ p,      // [K,1]
             const float* __restrict__ w0,     // [1]
             const float* __restrict__ w1,     // [VOCAB,1]
             float*       __restrict__ out)    // [B]
{
    // V tile in bf16, rows padded 64->72 shorts (144B) to break bank alignment
    __shared__ __align__(16) short Vsh[F][72];          // 4.6 KB
    __shared__ unsigned char pi_sh[NPAIR], pj_sh[NPAIR];
    __shared__ float fm_sh[F];
    __shared__ float wacc[4];

    const int b    = blockIdx.x;
    const int t    = threadIdx.x;
    const int lane = t & 63;
    const int wv   = t >> 6;
    const int c    = lane & 15;        // mfma "col" index
    const int quad = lane >> 4;        // mfma k-chunk / row-group index

    // ---- pair index tables (i<j, triu order) ----
    if (t < F) {
        int i = t;
        int base = i * (2 * F - i - 1) / 2;
        for (int j = i + 1; j < F; ++j) {
            pi_sh[base + (j - i - 1)] = (unsigned char)i;
            pj_sh[base + (j - i - 1)] = (unsigned char)j;
        }
    }

    // ---- gather V rows for this b, convert to bf16 in LDS ----
    {
        int f  = t >> 3;               // 0..31
        int cb = (t & 7) * 8;          // 0,8,...,56
        int idx = x[f * BATCH + b];
        const float4* src = (const float4*)&emb_v[idx * K + cb];
        float4 a0 = src[0], a1 = src[1];
        v8s w;
        w[0] = f2bf(a0.x); w[1] = f2bf(a0.y); w[2] = f2bf(a0.z); w[3] = f2bf(a0.w);
        w[4] = f2bf(a1.x); w[5] = f2bf(a1.y); w[6] = f2bf(a1.z); w[7] = f2bf(a1.w);
        *(v8s*)&Vsh[f][cb] = w;
    }
    // ---- first-order FM partials ----
    if (t < F) fm_sh[t] = w1[x[t * BATCH + b]];

    // ---- per-lane parameter preloads ----
    // B fragments of at_w: bfrag[nt][kk], element e holds at_w[kk*32+quad*8+e][nt*16+c]
    v8s bfrag[4][2];
    #pragma unroll
    for (int nt = 0; nt < 4; ++nt)
        #pragma unroll
        for (int kk = 0; kk < 2; ++kk)
            #pragma unroll
            for (int e = 0; e < 8; ++e)
                bfrag[nt][kk][e] = f2bf(at_w[(kk * 32 + quad * 8 + e) * H + nt * 16 + c]);

    float ab[4], ah[4];
    #pragma unroll
    for (int nt = 0; nt < 4; ++nt) {
        ab[nt] = at_b[nt * 16 + c];
        ah[nt] = at_h[nt * 16 + c];
    }
    float preg[16];                    // p[kk*32 + quad*8 + e]
    #pragma unroll
    for (int kk = 0; kk < 2; ++kk) {
        float4 p0 = *(const float4*)&p[kk * 32 + quad * 8];
        float4 p1 = *(const float4*)&p[kk * 32 + quad * 8 + 4];
        preg[kk * 8 + 0] = p0.x; preg[kk * 8 + 1] = p0.y;
        preg[kk * 8 + 2] = p0.z; preg[kk * 8 + 3] = p0.w;
        preg[kk * 8 + 4] = p1.x; preg[kk * 8 + 5] = p1.y;
        preg[kk * 8 + 6] = p1.z; preg[kk * 8 + 7] = p1.w;
    }

    __syncthreads();

    float accTot = 0.f;

    // each wave owns tile-rows wv, wv+4, ... (16 pairs each)
    for (int tr = wv; tr < NTROW; tr += 4) {
        int pr = tr * 16 + c;          // this lane's pair (A-operand row m = c)
        int pi = pi_sh[pr], pj = pj_sh[pr];

        // build A fragments (VV) in registers; accumulate q partial on the fly
        v8s af[2];
        float qp = 0.f;
        #pragma unroll
        for (int kk = 0; kk < 2; ++kk) {
            v8s vi = *(const v8s*)&Vsh[pi][kk * 32 + quad * 8];
            v8s vj = *(const v8s*)&Vsh[pj][kk * 32 + quad * 8];
            #pragma unroll
            for (int e = 0; e < 8; ++e) {
                float prod = bf2f(vi[e]) * bf2f(vj[e]);
                af[kk][e] = f2bf(prod);
                qp = fmaf(prod, preg[kk * 8 + e], qp);
            }
        }

        // hid_pre[m][h] via MFMA: D[m=quad*4+r][h=nt*16+c]
        v4f acc[4];
        #pragma unroll
        for (int nt = 0; nt < 4; ++nt) {
            acc[nt] = (v4f){0.f, 0.f, 0.f, 0.f};
            #pragma unroll
            for (int kk = 0; kk < 2; ++kk)
                acc[nt] = __builtin_amdgcn_mfma_f32_16x16x32_bf16(af[kk], bfrag[nt][kk], acc[nt], 0, 0, 0);
        }

        // score[m] = sum_h relu(hid_pre + at_b) * at_h
        float scr[4];
        #pragma unroll
        for (int r = 0; r < 4; ++r) {
            float s = 0.f;
            #pragma unroll
            for (int nt = 0; nt < 4; ++nt) {
                float pre = acc[nt][r] + ab[nt];
                s = fmaf(fmaxf(pre, 0.f), ah[nt], s);
            }
            s += __shfl_xor(s, 1);
            s += __shfl_xor(s, 2);
            s += __shfl_xor(s, 4);
            s += __shfl_xor(s, 8);
            scr[r] = s;                // score for pair m = quad*4 + r
        }
        // q[m=c]: reduce partials across quads
        qp += __shfl_xor(qp, 16);
        qp += __shfl_xor(qp, 32);

        // lane (quad,c) holds q for m=c and scores for m in [quad*4, quad*4+4)
        float sSel = (c & 2) ? ((c & 1) ? scr[3] : scr[2])
                             : ((c & 1) ? scr[1] : scr[0]);
        if ((c >> 2) == quad) accTot = fmaf(sSel, qp, accTot);
    }

    // wave reduce + cross-wave combine
    accTot += __shfl_xor(accTot, 1);
    accTot += __shfl_xor(accTot, 2);
    accTot += __shfl_xor(accTot, 4);
    accTot += __shfl_xor(accTot, 8);
    accTot += __shfl_xor(accTot, 16);
    accTot += __shfl_xor(accTot, 32);
    if (lane == 0) wacc[wv] = accTot;
    __syncthreads();

    if (t == 0) {
        float fm1 = w0[0];
        #pragma unroll
        for (int f = 0; f < F; ++f) fm1 += fm_sh[f];
        float logit = wacc[0] + wacc[1] + wacc[2] + wacc[3] + fm1;
        out[b] = 1.f / (1.f + expf(-logit));
    }
}

extern "C" void kernel_launch(void* const* d_in, const int* in_sizes, int n_in,
                              void* d_out, int out_size, void* d_ws, size_t ws_size,
                              hipStream_t stream) {
    const int*   x     = (const int*)  d_in[0];
    const float* emb_v = (const float*)d_in[1];
    const float* at_w  = (const float*)d_in[2];
    const float* at_b  = (const float*)d_in[3];
    const float* at_h  = (const float*)d_in[4];
    const float* p     = (const float*)d_in[5];
    const float* w0    = (const float*)d_in[6];
    const float* w1    = (const float*)d_in[7];
    float* out = (float*)d_out;

    afm_fwd<<<BATCH, 256, 0, stream>>>(x, emb_v, at_w, at_b, at_h, p, w0, w1, out);
}

// Round 3
// 108.067 us; speedup vs baseline: 3.2631x; 1.0140x over previous
//
#include <hip/hip_runtime.h>
#include <math.h>

#define F      32
#define BATCH  2048
#define K      64
#define H      64
#define NPAIR  496     // 32*31/2
#define NTROW  31      // 496/16 pair-tile rows of 16

// d_ws layout
#define WS_BFRAG_SHORTS (5 * 2 * 64 * 8)          // 5120 shorts = 10240 B
#define WS_PAIRS_OFF    10240                      // bytes; 31*64 ints = 7936 B

typedef float v4f __attribute__((ext_vector_type(4)));
typedef short v8s __attribute__((ext_vector_type(8)));

__device__ __forceinline__ float bf2f(short s) {
    union { unsigned u; float f; } v;
    v.u = ((unsigned)(unsigned short)s) << 16;
    return v.f;
}
__device__ __forceinline__ short f2bf(float f) {
    union { float f; unsigned u; } v; v.f = f;
    unsigned r = v.u + 0x7fffu + ((v.u >> 16) & 1u);   // RNE
    return (short)(r >> 16);
}

// ---------------------------------------------------------------------------
// Setup: transpose at_w (+ p as a replicated 5th tile) into MFMA B-fragment
// layout, and build the packed pair table. Runs once per call into d_ws.
// bfrag[nt][kk][lane][e] = nt<4 ? at_w[(kk*32+quad*8+e)*H + nt*16+c] : p[...]
// pairs[tr][lane] = pi | pj<<8   (replicated across the 4 quads)
// ---------------------------------------------------------------------------
__global__ void afm_setup(const float* __restrict__ at_w,
                          const float* __restrict__ p,
                          short* __restrict__ bfrag_ws,
                          int*   __restrict__ pairs_ws)
{
    int idx = blockIdx.x * blockDim.x + threadIdx.x;

    if (idx < 5 * 2 * 64) {                 // one v8s fragment chunk per thread
        int nt   = idx >> 7;                // 0..4
        int rem  = idx & 127;
        int kk   = rem >> 6;
        int lane = rem & 63;
        int quad = lane >> 4, c = lane & 15;
        v8s w;
        #pragma unroll
        for (int e = 0; e < 8; ++e) {
            int k = kk * 32 + quad * 8 + e;
            float val = (nt < 4) ? at_w[k * H + nt * 16 + c] : p[k];
            w[e] = f2bf(val);
        }
        *(v8s*)&bfrag_ws[idx * 8] = w;
    }

    if (idx < NTROW * 16) {                 // one (tr, c) pair entry per thread
        int tr = idx >> 4, c = idx & 15;
        int pr = tr * 16 + c;
        int i = 0, rem = pr;
        while (rem >= F - 1 - i) { rem -= F - 1 - i; ++i; }
        int j = i + 1 + rem;
        int packed = i | (j << 8);
        #pragma unroll
        for (int q = 0; q < 4; ++q)
            pairs_ws[tr * 64 + q * 16 + c] = packed;
    }
}

// ---------------------------------------------------------------------------
// Main kernel: one block per batch element.
// ---------------------------------------------------------------------------
__global__ __launch_bounds__(256)
void afm_fwd(const int*   __restrict__ x,      // [F,B]
             const float* __restrict__ emb_v,  // [VOCAB,K]
             const float* __restrict__ at_b,   // [H]
             const float* __restrict__ at_h,   // [H,1]
             const float* __restrict__ w0,     // [1]
             const float* __restrict__ w1,     // [VOCAB,1]
             const short* __restrict__ bfrag_ws,
             const int*   __restrict__ pairs_ws,
             float*       __restrict__ out)    // [B]
{
    __shared__ __align__(16) short Vsh[F][72];   // bf16 V rows, padded
    __shared__ float fm_sh[F];
    __shared__ float wacc[4];

    const int b    = blockIdx.x;
    const int t    = threadIdx.x;
    const int lane = t & 63;
    const int wv   = t >> 6;
    const int c    = lane & 15;
    const int quad = lane >> 4;

    // ---- gather V rows for this b, convert to bf16 in LDS ----
    {
        int f  = t >> 3;               // 0..31
        int cb = (t & 7) * 8;          // 0,8,...,56
        int idx = x[f * BATCH + b];
        const float4* src = (const float4*)&emb_v[idx * K + cb];
        float4 a0 = src[0], a1 = src[1];
        v8s w;
        w[0] = f2bf(a0.x); w[1] = f2bf(a0.y); w[2] = f2bf(a0.z); w[3] = f2bf(a0.w);
        w[4] = f2bf(a1.x); w[5] = f2bf(a1.y); w[6] = f2bf(a1.z); w[7] = f2bf(a1.w);
        *(v8s*)&Vsh[f][cb] = w;
    }
    if (t < F) fm_sh[t] = w1[x[t * BATCH + b]];

    // ---- B fragments: 10 coalesced 16B loads ----
    v8s bf[5][2];
    #pragma unroll
    for (int nt = 0; nt < 5; ++nt)
        #pragma unroll
        for (int kk = 0; kk < 2; ++kk)
            bf[nt][kk] = *(const v8s*)&bfrag_ws[((nt * 2 + kk) * 64 + lane) * 8];

    float ab[4], ah[4];
    #pragma unroll
    for (int nt = 0; nt < 4; ++nt) {
        ab[nt] = at_b[nt * 16 + c];
        ah[nt] = at_h[nt * 16 + c];
    }

    // ---- prefetch this lane's pair entries (coalesced) ----
    int prk[8];
    #pragma unroll
    for (int s = 0; s < 8; ++s) {
        int tr = wv + 4 * s;
        prk[s] = (tr < NTROW) ? pairs_ws[tr * 64 + lane] : 0;
    }

    __syncthreads();

    float accTot = 0.f;

    #pragma unroll
    for (int s = 0; s < 8; ++s) {
        int tr = wv + 4 * s;
        if (tr >= NTROW) break;        // wave-uniform
        int pi = prk[s] & 255, pj = (prk[s] >> 8) & 255;

        // A fragments: VV[m=c][k] built in registers from bf16 V tile
        v8s af[2];
        #pragma unroll
        for (int kk = 0; kk < 2; ++kk) {
            v8s vi = *(const v8s*)&Vsh[pi][kk * 32 + quad * 8];
            v8s vj = *(const v8s*)&Vsh[pj][kk * 32 + quad * 8];
            #pragma unroll
            for (int e = 0; e < 8; ++e)
                af[kk][e] = f2bf(bf2f(vi[e]) * bf2f(vj[e]));
        }

        // 5 B-tiles: 4 of at_w (h), 1 of replicated p (-> q in every lane)
        v4f acc[5];
        #pragma unroll
        for (int nt = 0; nt < 5; ++nt) {
            acc[nt] = (v4f){0.f, 0.f, 0.f, 0.f};
            #pragma unroll
            for (int kk = 0; kk < 2; ++kk)
                acc[nt] = __builtin_amdgcn_mfma_f32_16x16x32_bf16(af[kk], bf[nt][kk], acc[nt], 0, 0, 0);
        }

        // shuffle-free epilogue: lane-local partial of sum_m q[m]*score[m]
        #pragma unroll
        for (int r = 0; r < 4; ++r) {
            float sp = 0.f;
            #pragma unroll
            for (int nt = 0; nt < 4; ++nt)
                sp = fmaf(fmaxf(acc[nt][r] + ab[nt], 0.f), ah[nt], sp);
            accTot = fmaf(acc[4][r], sp, accTot);   // acc[4][r] = q[m], same in all 16 lanes of the quad-row
        }
    }

    // one reduction per block
    accTot += __shfl_xor(accTot, 1);
    accTot += __shfl_xor(accTot, 2);
    accTot += __shfl_xor(accTot, 4);
    accTot += __shfl_xor(accTot, 8);
    accTot += __shfl_xor(accTot, 16);
    accTot += __shfl_xor(accTot, 32);
    if (lane == 0) wacc[wv] = accTot;
    __syncthreads();

    if (t == 0) {
        float fm1 = w0[0];
        #pragma unroll
        for (int f = 0; f < F; ++f) fm1 += fm_sh[f];
        float logit = wacc[0] + wacc[1] + wacc[2] + wacc[3] + fm1;
        out[b] = 1.f / (1.f + expf(-logit));
    }
}

extern "C" void kernel_launch(void* const* d_in, const int* in_sizes, int n_in,
                              void* d_out, int out_size, void* d_ws, size_t ws_size,
                              hipStream_t stream) {
    const int*   x     = (const int*)  d_in[0];
    const float* emb_v = (const float*)d_in[1];
    const float* at_w  = (const float*)d_in[2];
    const float* at_b  = (const float*)d_in[3];
    const float* at_h  = (const float*)d_in[4];
    const float* p     = (const float*)d_in[5];
    const float* w0    = (const float*)d_in[6];
    const float* w1    = (const float*)d_in[7];
    float* out = (float*)d_out;

    short* bfrag_ws = (short*)d_ws;
    int*   pairs_ws = (int*)((char*)d_ws + WS_PAIRS_OFF);

    afm_setup<<<3, 256, 0, stream>>>(at_w, p, bfrag_ws, pairs_ws);
    afm_fwd<<<BATCH, 256, 0, stream>>>(x, emb_v, at_b, at_h, w0, w1,
                                       bfrag_ws, pairs_ws, out);
}

// Round 4
// 99.625 us; speedup vs baseline: 3.5396x; 1.0847x over previous
//
#include <hip/hip_runtime.h>
#include <math.h>

#define F      32
#define BATCH  2048
#define K      64
#define H      64
#define NPAIR  496     // 32*31/2
#define NTROW  31      // 496/16 pair-tile rows of 16

// d_ws layout: 5*2*64 v8h fragments (10240 B), then pair table (31*64 ints)
#define WS_PAIRS_OFF    10240

typedef float    v4f __attribute__((ext_vector_type(4)));
typedef _Float16 v8h __attribute__((ext_vector_type(8)));

// ---------------------------------------------------------------------------
// Setup: convert at_w (+ p replicated as a 5th N-tile) into f16 MFMA
// B-fragment layout; build packed pair table. Runs once per call into d_ws.
// ---------------------------------------------------------------------------
__global__ void afm_setup(const float* __restrict__ at_w,
                          const float* __restrict__ p,
                          _Float16* __restrict__ bfrag_ws,
                          int*      __restrict__ pairs_ws)
{
    int idx = blockIdx.x * blockDim.x + threadIdx.x;

    if (idx < 5 * 2 * 64) {                 // one v8h fragment per thread
        int nt   = idx >> 7;                // 0..4
        int rem  = idx & 127;
        int kk   = rem >> 6;
        int lane = rem & 63;
        int quad = lane >> 4, c = lane & 15;
        v8h w;
        #pragma unroll
        for (int e = 0; e < 8; ++e) {
            int k = kk * 32 + quad * 8 + e;
            float val = (nt < 4) ? at_w[k * H + nt * 16 + c] : p[k];
            w[e] = (_Float16)val;           // RNE
        }
        *(v8h*)&bfrag_ws[idx * 8] = w;
    }

    if (idx < NTROW * 16) {                 // one (tr, c) pair entry
        int tr = idx >> 4, c = idx & 15;
        int pr = tr * 16 + c;
        int i = 0, rem = pr;
        while (rem >= F - 1 - i) { rem -= F - 1 - i; ++i; }
        int j = i + 1 + rem;
        int packed = i | (j << 8);
        #pragma unroll
        for (int q = 0; q < 4; ++q)
            pairs_ws[tr * 64 + q * 16 + c] = packed;
    }
}

// ---------------------------------------------------------------------------
// Main kernel: one block per batch element. f16 datapath throughout.
// ---------------------------------------------------------------------------
__global__ __launch_bounds__(256)
void afm_fwd(const int*   __restrict__ x,      // [F,B]
             const float* __restrict__ emb_v,  // [VOCAB,K]
             const float* __restrict__ at_b,   // [H]
             const float* __restrict__ at_h,   // [H,1]
             const float* __restrict__ w0,     // [1]
             const float* __restrict__ w1,     // [VOCAB,1]
             const _Float16* __restrict__ bfrag_ws,
             const int*   __restrict__ pairs_ws,
             float*       __restrict__ out)    // [B]
{
    __shared__ __align__(16) _Float16 Vsh[F][72];   // f16 V rows, 144B stride
    __shared__ float fm_sh[F];
    __shared__ float wacc[4];

    const int b    = blockIdx.x;
    const int t    = threadIdx.x;
    const int lane = t & 63;
    const int wv   = t >> 6;
    const int c    = lane & 15;
    const int quad = lane >> 4;

    // ---- gather V rows for this b, convert fp32 -> f16 into LDS ----
    {
        int f  = t >> 3;               // 0..31
        int cb = (t & 7) * 8;          // 0,8,...,56
        int idx = x[f * BATCH + b];
        const float4* src = (const float4*)&emb_v[idx * K + cb];
        float4 a0 = src[0], a1 = src[1];
        v8h w;
        w[0] = (_Float16)a0.x; w[1] = (_Float16)a0.y;
        w[2] = (_Float16)a0.z; w[3] = (_Float16)a0.w;
        w[4] = (_Float16)a1.x; w[5] = (_Float16)a1.y;
        w[6] = (_Float16)a1.z; w[7] = (_Float16)a1.w;
        *(v8h*)&Vsh[f][cb] = w;
    }
    if (t < F) fm_sh[t] = w1[x[t * BATCH + b]];

    // ---- B fragments: 10 coalesced 16B loads ----
    v8h bf[5][2];
    #pragma unroll
    for (int nt = 0; nt < 5; ++nt)
        #pragma unroll
        for (int kk = 0; kk < 2; ++kk)
            bf[nt][kk] = *(const v8h*)&bfrag_ws[((nt * 2 + kk) * 64 + lane) * 8];

    float ab[4], ah[4];
    #pragma unroll
    for (int nt = 0; nt < 4; ++nt) {
        ab[nt] = at_b[nt * 16 + c];
        ah[nt] = at_h[nt * 16 + c];
    }

    // ---- prefetch this lane's pair entries (coalesced) ----
    int prk[8];
    #pragma unroll
    for (int s = 0; s < 8; ++s) {
        int tr = wv + 4 * s;
        prk[s] = (tr < NTROW) ? pairs_ws[tr * 64 + lane] : 0;
    }

    __syncthreads();

    float accTot = 0.f;

    // software-pipelined: load iter s+1's V rows behind iter s's MFMAs
    v8h vi0 = *(const v8h*)&Vsh[prk[0] & 255][quad * 8];
    v8h vj0 = *(const v8h*)&Vsh[(prk[0] >> 8) & 255][quad * 8];
    v8h vi1 = *(const v8h*)&Vsh[prk[0] & 255][32 + quad * 8];
    v8h vj1 = *(const v8h*)&Vsh[(prk[0] >> 8) & 255][32 + quad * 8];

    #pragma unroll
    for (int s = 0; s < 8; ++s) {
        v8h af0 = vi0 * vj0;           // 4x v_pk_mul_f16 each
        v8h af1 = vi1 * vj1;

        if (s < 7) {
            int pi = prk[s + 1] & 255, pj = (prk[s + 1] >> 8) & 255;
            vi0 = *(const v8h*)&Vsh[pi][quad * 8];
            vj0 = *(const v8h*)&Vsh[pj][quad * 8];
            vi1 = *(const v8h*)&Vsh[pi][32 + quad * 8];
            vj1 = *(const v8h*)&Vsh[pj][32 + quad * 8];
        }

        // 5 N-tiles: 4 of at_w, 1 of replicated p (q lands in every lane)
        v4f acc[5];
        #pragma unroll
        for (int nt = 0; nt < 4; ++nt)
            acc[nt] = (v4f){ab[nt], ab[nt], ab[nt], ab[nt]};   // bias pre-folded
        acc[4] = (v4f){0.f, 0.f, 0.f, 0.f};
        #pragma unroll
        for (int nt = 0; nt < 5; ++nt) {
            acc[nt] = __builtin_amdgcn_mfma_f32_16x16x32_f16(af0, bf[nt][0], acc[nt], 0, 0, 0);
            acc[nt] = __builtin_amdgcn_mfma_f32_16x16x32_f16(af1, bf[nt][1], acc[nt], 0, 0, 0);
        }

        if (wv + 4 * s < NTROW) {      // wave-uniform gate (false only wv=3,s=7)
            #pragma unroll
            for (int r = 0; r < 4; ++r) {
                float sp = 0.f;
                #pragma unroll
                for (int nt = 0; nt < 4; ++nt)
                    sp = fmaf(fmaxf(acc[nt][r], 0.f), ah[nt], sp);
                accTot = fmaf(acc[4][r], sp, accTot);   // acc[4][r] = q[m]
            }
        }
    }

    // one reduction per block
    accTot += __shfl_xor(accTot, 1);
    accTot += __shfl_xor(accTot, 2);
    accTot += __shfl_xor(accTot, 4);
    accTot += __shfl_xor(accTot, 8);
    accTot += __shfl_xor(accTot, 16);
    accTot += __shfl_xor(accTot, 32);
    if (lane == 0) wacc[wv] = accTot;
    __syncthreads();

    if (t == 0) {
        float fm1 = w0[0];
        #pragma unroll
        for (int f = 0; f < F; ++f) fm1 += fm_sh[f];
        float logit = wacc[0] + wacc[1] + wacc[2] + wacc[3] + fm1;
        out[b] = 1.f / (1.f + expf(-logit));
    }
}

extern "C" void kernel_launch(void* const* d_in, const int* in_sizes, int n_in,
                              void* d_out, int out_size, void* d_ws, size_t ws_size,
                              hipStream_t stream) {
    const int*   x     = (const int*)  d_in[0];
    const float* emb_v = (const float*)d_in[1];
    const float* at_w  = (const float*)d_in[2];
    const float* at_b  = (const float*)d_in[3];
    const float* at_h  = (const float*)d_in[4];
    const float* p     = (const float*)d_in[5];
    const float* w0    = (const float*)d_in[6];
    const float* w1    = (const float*)d_in[7];
    float* out = (float*)d_out;

    _Float16* bfrag_ws = (_Float16*)d_ws;
    int*      pairs_ws = (int*)((char*)d_ws + WS_PAIRS_OFF);

    afm_setup<<<3, 256, 0, stream>>>(at_w, p, bfrag_ws, pairs_ws);
    afm_fwd<<<BATCH, 256, 0, stream>>>(x, emb_v, at_b, at_h, w0, w1,
                                       bfrag_ws, pairs_ws, out);
}

// Round 5
// 99.404 us; speedup vs baseline: 3.5475x; 1.0022x over previous
//
#include <hip/hip_runtime.h>
#include <math.h>

#define F      32
#define BATCH  2048
#define K      64
#define H      64
#define NPAIR  496     // 32*31/2
#define NTROW  31      // 496/16 pair-tile rows of 16

// d_ws layout: 5*2*64 v8h fragments (10240 B), then pair table (31*64 ints)
#define WS_PAIRS_OFF    10240

typedef float    v4f __attribute__((ext_vector_type(4)));
typedef _Float16 v8h __attribute__((ext_vector_type(8)));

// ---------------------------------------------------------------------------
// Setup: convert at_w (+ p replicated as a 5th N-tile) into f16 MFMA
// B-fragment layout; build packed pair table. Runs once per call into d_ws.
// ---------------------------------------------------------------------------
__global__ void afm_setup(const float* __restrict__ at_w,
                          const float* __restrict__ p,
                          _Float16* __restrict__ bfrag_ws,
                          int*      __restrict__ pairs_ws)
{
    int idx = blockIdx.x * blockDim.x + threadIdx.x;

    if (idx < 5 * 2 * 64) {                 // one v8h fragment per thread
        int nt   = idx >> 7;                // 0..4
        int rem  = idx & 127;
        int kk   = rem >> 6;
        int lane = rem & 63;
        int quad = lane >> 4, c = lane & 15;
        v8h w;
        #pragma unroll
        for (int e = 0; e < 8; ++e) {
            int k = kk * 32 + quad * 8 + e;
            float val = (nt < 4) ? at_w[k * H + nt * 16 + c] : p[k];
            w[e] = (_Float16)val;           // RNE
        }
        *(v8h*)&bfrag_ws[idx * 8] = w;
    }

    if (idx < NTROW * 16) {                 // one (tr, c) pair entry
        int tr = idx >> 4, c = idx & 15;
        int pr = tr * 16 + c;
        int i = 0, rem = pr;
        while (rem >= F - 1 - i) { rem -= F - 1 - i; ++i; }
        int j = i + 1 + rem;
        int packed = i | (j << 8);
        #pragma unroll
        for (int q = 0; q < 4; ++q)
            pairs_ws[tr * 64 + q * 16 + c] = packed;
    }
}

// ---------------------------------------------------------------------------
// Main kernel: one block per batch element. f16 datapath, MFMA inner loop.
// __launch_bounds__(256,4): cap VGPR at 128 so we keep 4 waves/SIMD.
// ---------------------------------------------------------------------------
__global__ __launch_bounds__(256, 4)
void afm_fwd(const int*   __restrict__ x,      // [F,B]
             const float* __restrict__ emb_v,  // [VOCAB,K]
             const float* __restrict__ at_b,   // [H]
             const float* __restrict__ at_h,   // [H,1]
             const float* __restrict__ w0,     // [1]
             const float* __restrict__ w1,     // [VOCAB,1]
             const _Float16* __restrict__ bfrag_ws,
             const int*   __restrict__ pairs_ws,
             float*       __restrict__ out)    // [B]
{
    __shared__ __align__(16) _Float16 Vsh[F][72];   // f16 V rows, 144B stride
    __shared__ float fm_sh[F];
    __shared__ float wacc[4];

    const int b    = blockIdx.x;
    const int t    = threadIdx.x;
    const int lane = t & 63;
    const int wv   = t >> 6;
    const int c    = lane & 15;

    // ---- independent loads first: B fragments, pair entry, epilogue params ----
    v8h bf[5][2];
    #pragma unroll
    for (int nt = 0; nt < 5; ++nt)
        #pragma unroll
        for (int kk = 0; kk < 2; ++kk)
            bf[nt][kk] = *(const v8h*)&bfrag_ws[((nt * 2 + kk) * 64 + lane) * 8];

    int prkNxt = pairs_ws[wv * 64 + lane];   // iter-0 pair entry

    float ah[4];
    v4f abv[5];
    #pragma unroll
    for (int nt = 0; nt < 4; ++nt) {
        float abn = at_b[nt * 16 + c];
        ah[nt]  = at_h[nt * 16 + c];
        abv[nt] = (v4f){abn, abn, abn, abn};  // bias folded into MFMA C operand
    }
    abv[4] = (v4f){0.f, 0.f, 0.f, 0.f};

    // ---- dependent chain: x -> emb_v gather -> f16 LDS tile ----
    {
        int f  = t >> 3;               // 0..31
        int cb = (t & 7) * 8;          // 0,8,...,56
        int idx = x[f * BATCH + b];
        const float4* src = (const float4*)&emb_v[idx * K + cb];
        float4 a0 = src[0], a1 = src[1];
        v8h w;
        w[0] = (_Float16)a0.x; w[1] = (_Float16)a0.y;
        w[2] = (_Float16)a0.z; w[3] = (_Float16)a0.w;
        w[4] = (_Float16)a1.x; w[5] = (_Float16)a1.y;
        w[6] = (_Float16)a1.z; w[7] = (_Float16)a1.w;
        *(v8h*)&Vsh[f][cb] = w;
    }
    if (t < F) fm_sh[t] = w1[x[t * BATCH + b]];

    __syncthreads();

    float accTot = 0.f;
    const int quad = lane >> 4;

    // rolling 1-deep prefetch of pair entry + V-row fragments
    {
        int pi = prkNxt & 255, pj = (prkNxt >> 8) & 255;
        prkNxt = pairs_ws[(wv + 4) * 64 + lane];   // harmless overread row for wv=3 handled below
        v8h vi0 = *(const v8h*)&Vsh[pi][quad * 8];
        v8h vj0 = *(const v8h*)&Vsh[pj][quad * 8];
        v8h vi1 = *(const v8h*)&Vsh[pi][32 + quad * 8];
        v8h vj1 = *(const v8h*)&Vsh[pj][32 + quad * 8];

        #pragma unroll
        for (int s = 0; s < 8; ++s) {
            v8h af0 = vi0 * vj0;           // 4x v_pk_mul_f16 each
            v8h af1 = vi1 * vj1;

            if (s < 7) {
                int npi = prkNxt & 255, npj = (prkNxt >> 8) & 255;
                if (s < 6) {
                    int tr2 = wv + 4 * (s + 2);
                    prkNxt = pairs_ws[(tr2 < NTROW ? tr2 : 0) * 64 + lane];
                }
                vi0 = *(const v8h*)&Vsh[npi][quad * 8];
                vj0 = *(const v8h*)&Vsh[npj][quad * 8];
                vi1 = *(const v8h*)&Vsh[npi][32 + quad * 8];
                vj1 = *(const v8h*)&Vsh[npj][32 + quad * 8];
            }

            // 5 N-tiles; bias enters as the C operand of the first MFMA
            v4f acc[5];
            #pragma unroll
            for (int nt = 0; nt < 5; ++nt) {
                v4f a = __builtin_amdgcn_mfma_f32_16x16x32_f16(af0, bf[nt][0], abv[nt], 0, 0, 0);
                acc[nt] = __builtin_amdgcn_mfma_f32_16x16x32_f16(af1, bf[nt][1], a, 0, 0, 0);
            }

            if (wv + 4 * s < NTROW) {      // wave-uniform (false only wv=3,s=7)
                #pragma unroll
                for (int r = 0; r < 4; ++r) {
                    float sp = 0.f;
                    #pragma unroll
                    for (int nt = 0; nt < 4; ++nt)
                        sp = fmaf(fmaxf(acc[nt][r], 0.f), ah[nt], sp);
                    accTot = fmaf(acc[4][r], sp, accTot);   // acc[4][r] = q[m]
                }
            }
        }
    }

    // one reduction per block
    accTot += __shfl_xor(accTot, 1);
    accTot += __shfl_xor(accTot, 2);
    accTot += __shfl_xor(accTot, 4);
    accTot += __shfl_xor(accTot, 8);
    accTot += __shfl_xor(accTot, 16);
    accTot += __shfl_xor(accTot, 32);
    if (lane == 0) wacc[wv] = accTot;
    __syncthreads();

    if (t == 0) {
        float fm1 = w0[0];
        #pragma unroll
        for (int f = 0; f < F; ++f) fm1 += fm_sh[f];
        float logit = wacc[0] + wacc[1] + wacc[2] + wacc[3] + fm1;
        out[b] = 1.f / (1.f + expf(-logit));
    }
}

extern "C" void kernel_launch(void* const* d_in, const int* in_sizes, int n_in,
                              void* d_out, int out_size, void* d_ws, size_t ws_size,
                              hipStream_t stream) {
    const int*   x     = (const int*)  d_in[0];
    const float* emb_v = (const float*)d_in[1];
    const float* at_w  = (const float*)d_in[2];
    const float* at_b  = (const float*)d_in[3];
    const float* at_h  = (const float*)d_in[4];
    const float* p     = (const float*)d_in[5];
    const float* w0    = (const float*)d_in[6];
    const float* w1    = (const float*)d_in[7];
    float* out = (float*)d_out;

    _Float16* bfrag_ws = (_Float16*)d_ws;
    int*      pairs_ws = (int*)((char*)d_ws + WS_PAIRS_OFF);

    afm_setup<<<3, 256, 0, stream>>>(at_w, p, bfrag_ws, pairs_ws);
    afm_fwd<<<BATCH, 256, 0, stream>>>(x, emb_v, at_b, at_h, w0, w1,
                                       bfrag_ws, pairs_ws, out);
}

// Round 7
// 98.649 us; speedup vs baseline: 3.5747x; 1.0077x over previous
//
#include <hip/hip_runtime.h>
#include <math.h>

#define F      32
#define BATCH  2048
#define K      64
#define H      64
#define NPAIR  496     // 32*31/2
#define NTROW  31      // 496/16 pair-tile rows
#define EPB    4       // batch elems per block (one per wave)
#define NBLK   (BATCH / EPB)

typedef float    v4f __attribute__((ext_vector_type(4)));
typedef _Float16 v8h __attribute__((ext_vector_type(8)));
typedef __fp16   h2  __attribute__((ext_vector_type(2)));   // cvt_pkrtz return type

union V8H { v8h v; h2 h[4]; };

// ---------------------------------------------------------------------------
// Single kernel. Block = 4 waves = 4 batch elems; wave wv owns elem b0+wv.
// Pair table + B-fragments built per block (L2-hot, amortized over 4 elems).
// ---------------------------------------------------------------------------
__global__ __launch_bounds__(256, 4)
void afm_fwd(const int*   __restrict__ x,      // [F,B]
             const float* __restrict__ emb_v,  // [VOCAB,K]
             const float* __restrict__ at_w,   // [K,H]
             const float* __restrict__ at_b,   // [H]
             const float* __restrict__ at_h,   // [H,1]
             const float* __restrict__ p,      // [K,1]
             const float* __restrict__ w0,     // [1]
             const float* __restrict__ w1,     // [VOCAB,1]
             float*       __restrict__ out)    // [B]
{
    __shared__ __align__(16) _Float16 Vsh[EPB][F][72];   // 18.4 KB, 144B rows
    __shared__ unsigned short pairs_sh[NPAIR + 16];
    __shared__ float fm_sh[EPB * F];

    const int t    = threadIdx.x;
    const int lane = t & 63;
    const int wv   = t >> 6;
    const int c    = lane & 15;
    const int quad = lane >> 4;
    const int b0   = blockIdx.x * EPB;

    // ---- pair table: closed-form unrank of triu index, 2 entries/thread ----
    if (t < NPAIR / 2) {
        #pragma unroll
        for (int u2 = 0; u2 < 2; ++u2) {
            int pr = t * 2 + u2;
            int r  = NPAIR - 1 - pr;
            int u  = (int)((sqrtf((float)(8 * r + 1)) - 1.0f) * 0.5f);
            if (u * (u + 1) / 2 > r) --u;                 // fp guard
            if ((u + 1) * (u + 2) / 2 <= r) ++u;
            int i   = F - 2 - u;
            int off = r - u * (u + 1) / 2;
            int j   = F - 1 - off;
            pairs_sh[pr] = (unsigned short)(i | (j << 8));
        }
    }

    // ---- gather V rows for 4 elems, fp32 -> f16 into LDS ----
    {
        int row  = t >> 1;             // 0..127
        int elem = row >> 5, f = row & 31, half = t & 1;
        int idx  = x[f * BATCH + b0 + elem];
        const float4* src = (const float4*)&emb_v[idx * K + half * 32];
        #pragma unroll
        for (int j4 = 0; j4 < 4; ++j4) {
            float4 a = src[j4 * 2], b = src[j4 * 2 + 1];
            V8H w;
            w.h[0] = __builtin_amdgcn_cvt_pkrtz(a.x, a.y);
            w.h[1] = __builtin_amdgcn_cvt_pkrtz(a.z, a.w);
            w.h[2] = __builtin_amdgcn_cvt_pkrtz(b.x, b.y);
            w.h[3] = __builtin_amdgcn_cvt_pkrtz(b.z, b.w);
            *(v8h*)&Vsh[elem][f][half * 32 + j4 * 8] = w.v;
        }
    }
    if (t < EPB * F) {
        int elem = t >> 5, f = t & 31;
        fm_sh[t] = w1[x[f * BATCH + b0 + elem]];
    }

    // ---- B fragments built directly from at_w (+ p as 5th N-tile) ----
    v8h bf[5][2];
    #pragma unroll
    for (int kk = 0; kk < 2; ++kk) {
        #pragma unroll
        for (int nt = 0; nt < 4; ++nt) {
            V8H w;
            #pragma unroll
            for (int e = 0; e < 8; e += 2) {
                int k = kk * 32 + quad * 8 + e;
                w.h[e >> 1] = __builtin_amdgcn_cvt_pkrtz(
                    at_w[k * H + nt * 16 + c], at_w[(k + 1) * H + nt * 16 + c]);
            }
            bf[nt][kk] = w.v;
        }
        float4 p0 = *(const float4*)&p[kk * 32 + quad * 8];
        float4 p1 = *(const float4*)&p[kk * 32 + quad * 8 + 4];
        V8H w;
        w.h[0] = __builtin_amdgcn_cvt_pkrtz(p0.x, p0.y);
        w.h[1] = __builtin_amdgcn_cvt_pkrtz(p0.z, p0.w);
        w.h[2] = __builtin_amdgcn_cvt_pkrtz(p1.x, p1.y);
        w.h[3] = __builtin_amdgcn_cvt_pkrtz(p1.z, p1.w);
        bf[4][kk] = w.v;
    }

    float ah[4];
    v4f abv[5];
    #pragma unroll
    for (int nt = 0; nt < 4; ++nt) {
        float abn = at_b[nt * 16 + c];
        ah[nt]  = at_h[nt * 16 + c];
        abv[nt] = (v4f){abn, abn, abn, abn};   // bias as MFMA C operand
    }
    abv[4] = (v4f){0.f, 0.f, 0.f, 0.f};

    __syncthreads();

    // ---- main loop: wave wv, elem b0+wv, all 31 tile-rows ----
    const _Float16* Vw = &Vsh[wv][0][0];
    float accTot = 0.f;

    unsigned short pk = pairs_sh[c];           // tr = 0
    int pi = pk & 255, pj = pk >> 8;
    v8h vi0 = *(const v8h*)&Vw[pi * 72 + quad * 8];
    v8h vj0 = *(const v8h*)&Vw[pj * 72 + quad * 8];
    v8h vi1 = *(const v8h*)&Vw[pi * 72 + 32 + quad * 8];
    v8h vj1 = *(const v8h*)&Vw[pj * 72 + 32 + quad * 8];

    for (int tr = 0; tr < NTROW; ++tr) {
        v8h af0 = vi0 * vj0;                   // v_pk_mul_f16
        v8h af1 = vi1 * vj1;

        if (tr < NTROW - 1) {                  // rolling 1-deep prefetch
            pk = pairs_sh[(tr + 1) * 16 + c];
            pi = pk & 255; pj = pk >> 8;
            vi0 = *(const v8h*)&Vw[pi * 72 + quad * 8];
            vj0 = *(const v8h*)&Vw[pj * 72 + quad * 8];
            vi1 = *(const v8h*)&Vw[pi * 72 + 32 + quad * 8];
            vj1 = *(const v8h*)&Vw[pj * 72 + 32 + quad * 8];
        }

        v4f acc[5];
        #pragma unroll
        for (int nt = 0; nt < 5; ++nt) {
            v4f a = __builtin_amdgcn_mfma_f32_16x16x32_f16(af0, bf[nt][0], abv[nt], 0, 0, 0);
            acc[nt] = __builtin_amdgcn_mfma_f32_16x16x32_f16(af1, bf[nt][1], a, 0, 0, 0);
        }

        #pragma unroll
        for (int r = 0; r < 4; ++r) {
            float sp = 0.f;
            #pragma unroll
            for (int nt = 0; nt < 4; ++nt)
                sp = fmaf(fmaxf(acc[nt][r], 0.f), ah[nt], sp);
            accTot = fmaf(acc[4][r], sp, accTot);   // acc[4][r] = q[m]
        }
    }

    // ---- per-wave epilogue: fold in fm1 partials, reduce, store ----
    accTot += (lane < F) ? fm_sh[wv * F + lane] : 0.f;
    accTot += __shfl_xor(accTot, 1);
    accTot += __shfl_xor(accTot, 2);
    accTot += __shfl_xor(accTot, 4);
    accTot += __shfl_xor(accTot, 8);
    accTot += __shfl_xor(accTot, 16);
    accTot += __shfl_xor(accTot, 32);
    if (lane == 0) {
        float logit = accTot + w0[0];
        out[b0 + wv] = 1.f / (1.f + expf(-logit));
    }
}

extern "C" void kernel_launch(void* const* d_in, const int* in_sizes, int n_in,
                              void* d_out, int out_size, void* d_ws, size_t ws_size,
                              hipStream_t stream) {
    const int*   x     = (const int*)  d_in[0];
    const float* emb_v = (const float*)d_in[1];
    const float* at_w  = (const float*)d_in[2];
    const float* at_b  = (const float*)d_in[3];
    const float* at_h  = (const float*)d_in[4];
    const float* p     = (const float*)d_in[5];
    const float* w0    = (const float*)d_in[6];
    const float* w1    = (const float*)d_in[7];
    float* out = (float*)d_out;

    afm_fwd<<<NBLK, 256, 0, stream>>>(x, emb_v, at_w, at_b, at_h, p, w0, w1, out);
}